// Round 2
// baseline (593.410 us; speedup 1.0000x reference)
//
#include <hip/hip_runtime.h>

#define DD 192
#define SROWS 16

// dot of a 192-long f32 row with a 192-long f32 vector (LDS)
__device__ __forceinline__ float dot192f(const float* __restrict__ row,
                                         const float* __restrict__ v) {
    const float4* p = (const float4*)row;
    float a0 = 0.f, a1 = 0.f, a2 = 0.f, a3 = 0.f;
#pragma unroll
    for (int c = 0; c < 48; c++) {
        float4 q = p[c];
        a0 = fmaf(q.x, v[4 * c + 0], a0);
        a1 = fmaf(q.y, v[4 * c + 1], a1);
        a2 = fmaf(q.z, v[4 * c + 2], a2);
        a3 = fmaf(q.w, v[4 * c + 3], a3);
    }
    return (a0 + a1) + (a2 + a3);
}

// ---------- generic GEMM stage: C[s,i] = post( sum_j A[s,j]*W[i*192+j] + bias[i] ) ----------
// POST: 0 none, 1 LN, 2 LN+ReLU.
// COLSUM: atomicAdd per-column sums of C (pre-post) into colsum[192].
template <int POST, bool COLSUM>
__global__ __launch_bounds__(256) void stage_k(
    const float* __restrict__ A, const float* __restrict__ Wf,
    const float* __restrict__ bias, const float* __restrict__ g,
    const float* __restrict__ b, float* __restrict__ outF,
    float* __restrict__ colsum) {
    __shared__ float At[SROWS][196];   // stride 196: float4-aligned & conflict-free
    __shared__ float WcT[32][193];     // W chunk transposed: WcT[j][i]
    const int tid = threadIdx.x;
    const int tr = tid >> 5, tc = tid & 31;
    const int r0 = blockIdx.x * SROWS;

    // stage A tile (16 rows x 192) via float4
    {
        const float4* Ap = (const float4*)(A + (size_t)r0 * DD);
        for (int e = tid; e < (SROWS * DD / 4); e += 256) {
            int r = e / 48, j4 = e % 48;
            float4 v = Ap[e];
            *(float4*)&At[r][j4 * 4] = v;
        }
    }
    float acc0[6], acc1[6];
#pragma unroll
    for (int ci = 0; ci < 6; ci++) {
        float bv = bias[ci * 32 + tc];
        acc0[ci] = bv;
        acc1[ci] = bv;
    }
    __syncthreads();

    const int ra = 2 * tr, rb = 2 * tr + 1;
    for (int jc = 0; jc < 6; jc++) {
        if (jc) __syncthreads();
        const int j0 = jc * 32;
        for (int e = tid; e < DD * 32; e += 256) {
            int i = e >> 5, jj = e & 31;
            WcT[jj][i] = Wf[i * DD + j0 + jj];
        }
        __syncthreads();
#pragma unroll
        for (int j = 0; j < 32; j++) {
            float a0v = At[ra][j0 + j];
            float a1v = At[rb][j0 + j];
#pragma unroll
            for (int ci = 0; ci < 6; ci++) {
                float w = WcT[j][ci * 32 + tc];
                acc0[ci] = fmaf(a0v, w, acc0[ci]);
                acc1[ci] = fmaf(a1v, w, acc1[ci]);
            }
        }
    }

    if (POST == 0) {
#pragma unroll
        for (int ci = 0; ci < 6; ci++) {
            int i = ci * 32 + tc;
            outF[(size_t)(r0 + ra) * DD + i] = acc0[ci];
            outF[(size_t)(r0 + rb) * DD + i] = acc1[ci];
        }
        if (COLSUM) {
            __syncthreads();
            float* cs = &WcT[0][0];   // reuse as scratch [8][192]
#pragma unroll
            for (int ci = 0; ci < 6; ci++)
                cs[tr * DD + ci * 32 + tc] = acc0[ci] + acc1[ci];
            __syncthreads();
            if (tid < DD) {
                float s = 0.f;
#pragma unroll
                for (int t = 0; t < 8; t++) s += cs[t * DD + tid];
                atomicAdd(&colsum[tid], s);
            }
        }
    } else {
        // LayerNorm over each row (192 values spread over the 32 lanes of this tr-group)
        float s0 = 0, q0 = 0, s1 = 0, q1 = 0;
#pragma unroll
        for (int ci = 0; ci < 6; ci++) {
            s0 += acc0[ci]; q0 += acc0[ci] * acc0[ci];
            s1 += acc1[ci]; q1 += acc1[ci] * acc1[ci];
        }
#pragma unroll
        for (int m = 16; m >= 1; m >>= 1) {
            s0 += __shfl_xor(s0, m); q0 += __shfl_xor(q0, m);
            s1 += __shfl_xor(s1, m); q1 += __shfl_xor(q1, m);
        }
        const float inv = 1.f / 192.f;
        float m0 = s0 * inv, v0 = q0 * inv - m0 * m0;
        float m1 = s1 * inv, v1 = q1 * inv - m1 * m1;
        float rs0 = rsqrtf(v0 + 1e-5f), rs1 = rsqrtf(v1 + 1e-5f);
#pragma unroll
        for (int ci = 0; ci < 6; ci++) {
            int i = ci * 32 + tc;
            float gg = g[i], bb = b[i];
            float y0 = (acc0[ci] - m0) * rs0 * gg + bb;
            float y1 = (acc1[ci] - m1) * rs1 * gg + bb;
            if (POST == 2) { y0 = fmaxf(y0, 0.f); y1 = fmaxf(y1, 0.f); }
            outF[(size_t)(r0 + ra) * DD + i] = y0;
            outF[(size_t)(r0 + rb) * DD + i] = y1;
        }
    }
}

// ---------- feat hypernet: a_pre[i] = sum_j xm[j]*(feat_W[i,j] + feat_AW[k]@xm + feat_Ab[k]) + feat_b[i] ----------
__global__ __launch_bounds__(256) void feat_k(
    const float* __restrict__ AW, const float* __restrict__ Ab,
    const float* __restrict__ Wm, const float* __restrict__ fb,
    const float* __restrict__ xm_sum, float* __restrict__ a_pre) {
    __shared__ float xm[DD];
    __shared__ float red[2];
    const int tid = threadIdx.x;
    if (tid < DD) xm[tid] = xm_sum[tid] * (1.f / 4096.f);
    if (tid < 2) red[tid] = 0.f;
    __syncthreads();
    int k = blockIdx.x * 256 + tid;  // < 36864
    int i = k / DD, j = k - i * DD;
    float val = dot192f(AW + (size_t)k * DD, xm) + Ab[k] + Wm[k];
    float contrib = xm[j] * val;
    if (j == 0) contrib += fb[i];
    int i0 = (blockIdx.x * 256) / DD;   // block spans at most 2 distinct i (256+128 < 384)
    atomicAdd(&red[i - i0], contrib);
    __syncthreads();
    if (tid < 2) {
        int ii = i0 + tid;
        if (ii < DD) atomicAdd(&a_pre[ii], red[tid]);
    }
}

// ---------- tiny vector kernel: LN(a_pre) -> a0; gate softmax; b_moe ----------
__global__ __launch_bounds__(192) void vec_k(
    const float* __restrict__ a_pre, const float* __restrict__ an_g,
    const float* __restrict__ an_b, const float* __restrict__ gate_W,
    const float* __restrict__ gate_b, const float* __restrict__ ex_b,
    float* __restrict__ a0g, float* __restrict__ gateg, float* __restrict__ b_moe) {
    __shared__ float a0s[DD];
    __shared__ float lg[8];
    __shared__ float red[6];
    const int t = threadIdx.x;
    float v = a_pre[t];
    float s = v, q = v * v;
#pragma unroll
    for (int m = 32; m >= 1; m >>= 1) {
        s += __shfl_xor(s, m);
        q += __shfl_xor(q, m);
    }
    if ((t & 63) == 0) { red[t >> 6] = s; red[3 + (t >> 6)] = q; }
    __syncthreads();
    float S = red[0] + red[1] + red[2];
    float Q = red[3] + red[4] + red[5];
    float mean = S / 192.f, var = Q / 192.f - mean * mean;
    float rs = rsqrtf(var + 1e-5f);
    float a0v = (v - mean) * rs * an_g[t] + an_b[t];
    a0s[t] = a0v;
    a0g[t] = a0v;
    __syncthreads();
    if (t < 8) {
        float acc = gate_b[t];
        for (int j = 0; j < DD; j++) acc = fmaf(a0s[j], gate_W[t * DD + j], acc);
        lg[t] = acc;
    }
    __syncthreads();
    if (t == 0) {
        float mx = lg[0];
        for (int e = 1; e < 8; e++) mx = fmaxf(mx, lg[e]);
        float sum = 0.f, ex[8];
        for (int e = 0; e < 8; e++) { ex[e] = expf(lg[e] - mx); sum += ex[e]; }
        for (int e = 0; e < 8; e++) lg[e] = ex[e] / sum;
    }
    __syncthreads();
    if (t < 8) gateg[t] = lg[t];
    float bm = 0.f;
#pragma unroll
    for (int e = 0; e < 8; e++) bm += lg[e] * ex_b[e * DD + t];
    b_moe[t] = bm;
}

// ---------- build combined weights Wt, Wc, Wmoe ----------
__global__ __launch_bounds__(256) void build_k(
    const float* __restrict__ tm_W, const float* __restrict__ tm_AW,
    const float* __restrict__ tm_Ab, const float* __restrict__ cm_W,
    const float* __restrict__ cm_AW, const float* __restrict__ cm_Ab,
    const float* __restrict__ ex_W, const float* __restrict__ ex_AW,
    const float* __restrict__ ex_Ab, const float* __restrict__ a0g,
    const float* __restrict__ gateg, float* __restrict__ Wt, float* __restrict__ Wc,
    float* __restrict__ Wmoe) {
    __shared__ float a0[DD];
    const int t = threadIdx.x;
    if (t < DD) a0[t] = a0g[t];
    __syncthreads();
    const int b = blockIdx.x;
    if (b < 144) {
        int k = b * 256 + t;
        Wt[k] = tm_W[k] + dot192f(tm_AW + (size_t)k * DD, a0) + tm_Ab[k];
    } else if (b < 288) {
        int k = (b - 144) * 256 + t;
        Wc[k] = cm_W[k] + dot192f(cm_AW + (size_t)k * DD, a0) + cm_Ab[k];
    } else {
        int b2 = b - 288;
        int e = b2 / 144, c = b2 - e * 144;
        int k = c * 256 + t;
        size_t ek = (size_t)e * 36864 + k;
        float val = ex_W[ek] + dot192f(ex_AW + ek * DD, a0) + ex_Ab[ek];
        atomicAdd(&Wmoe[k], gateg[e] * val);
    }
}

// ---------- launch ----------
extern "C" void kernel_launch(void* const* d_in, const int* in_sizes, int n_in,
                              void* d_out, int out_size, void* d_ws, size_t ws_size,
                              hipStream_t stream) {
    (void)in_sizes; (void)n_in; (void)out_size; (void)ws_size;
    const float* x       = (const float*)d_in[0];
    const float* W_in    = (const float*)d_in[1];
    const float* b_in    = (const float*)d_in[2];
    const float* feat_W  = (const float*)d_in[3];
    const float* feat_b  = (const float*)d_in[4];
    const float* feat_AW = (const float*)d_in[5];
    const float* feat_Ab = (const float*)d_in[6];
    const float* an_g    = (const float*)d_in[7];
    const float* an_b    = (const float*)d_in[8];
    const float* tm_W    = (const float*)d_in[9];
    const float* tm_b    = (const float*)d_in[10];
    const float* tm_AW   = (const float*)d_in[11];
    const float* tm_Ab   = (const float*)d_in[12];
    const float* tn_g    = (const float*)d_in[13];
    const float* tn_b    = (const float*)d_in[14];
    const float* cm_W    = (const float*)d_in[15];
    const float* cm_b    = (const float*)d_in[16];
    const float* cm_AW   = (const float*)d_in[17];
    const float* cm_Ab   = (const float*)d_in[18];
    const float* cn_g    = (const float*)d_in[19];
    const float* cn_b    = (const float*)d_in[20];
    const float* pm_W    = (const float*)d_in[21];
    const float* pm_b    = (const float*)d_in[22];
    const float* gate_W  = (const float*)d_in[23];
    const float* gate_b  = (const float*)d_in[24];
    const float* ex_W    = (const float*)d_in[25];
    const float* ex_b    = (const float*)d_in[26];
    const float* ex_AW   = (const float*)d_in[27];
    const float* ex_Ab   = (const float*)d_in[28];
    const float* mn_g    = (const float*)d_in[29];
    const float* mn_b    = (const float*)d_in[30];
    const float* out_W   = (const float*)d_in[31];
    const float* out_b   = (const float*)d_in[32];

    float* ws = (float*)d_ws;
    float* B0     = ws;               // 786432 floats
    float* B1     = ws + 786432;      // 786432 floats
    float* xm_sum = ws + 1572864;     // 192   [zeroed]
    float* a_pre  = ws + 1573056;     // 192   [zeroed]
    float* Wmoe   = ws + 1573248;     // 36864 [zeroed]
    float* Wt     = ws + 1610112;     // 36864
    float* Wc     = ws + 1646976;     // 36864
    float* a0     = ws + 1683840;     // 192
    float* gate   = ws + 1684032;     // 8
    float* b_moe  = ws + 1684040;     // 192
    // total: 1684232 floats = 6.74 MB

    hipMemsetAsync(xm_sum, 0, (size_t)(192 + 192 + 36864) * sizeof(float), stream);

    // h = x @ W_in^T + b_in ; column-sums for xm   (x -> B0)
    stage_k<0, true><<<256, 256, 0, stream>>>(x, W_in, b_in, nullptr, nullptr, B0, xm_sum);
    feat_k<<<144, 256, 0, stream>>>(feat_AW, feat_Ab, feat_W, feat_b, xm_sum, a_pre);
    vec_k<<<1, 192, 0, stream>>>(a_pre, an_g, an_b, gate_W, gate_b, ex_b, a0, gate, b_moe);
    build_k<<<1440, 256, 0, stream>>>(tm_W, tm_AW, tm_Ab, cm_W, cm_AW, cm_Ab, ex_W, ex_AW,
                                      ex_Ab, a0, gate, Wt, Wc, Wmoe);
    // t = LN(h @ Wt^T + tm_b)        (B0 -> B1)
    stage_k<1, false><<<256, 256, 0, stream>>>(B0, Wt, tm_b, tn_g, tn_b, B1, nullptr);
    // c = LN(t @ Wc^T + cm_b)        (B1 -> B0)
    stage_k<1, false><<<256, 256, 0, stream>>>(B1, Wc, cm_b, cn_g, cn_b, B0, nullptr);
    // m = c @ pm_W^T + pm_b          (B0 -> B1)
    stage_k<0, false><<<256, 256, 0, stream>>>(B0, pm_W, pm_b, nullptr, nullptr, B1, nullptr);
    // eo = relu(LN(m @ Wmoe^T + b_moe))   (B1 -> B0)
    stage_k<2, false><<<256, 256, 0, stream>>>(B1, Wmoe, b_moe, mn_g, mn_b, B0, nullptr);
    // out = eo @ out_W^T + out_b     (B0 -> d_out, f32)
    stage_k<0, false><<<256, 256, 0, stream>>>(B0, out_W, out_b, nullptr, nullptr,
                                               (float*)d_out, nullptr);
}

// Round 3
// 566.922 us; speedup vs baseline: 1.0467x; 1.0467x over previous
//
#include <hip/hip_runtime.h>

#define DD 192

// =======================================================================
// stage2_k: C[s,i] = sum_j A'[s,j] * W[i,j] + bias[i]
//   A' = A (LNL=0), LN(A) (LNL=1), relu(LN(A)) (LNL=2), LN params stats_in/lng/lnb
//   EMIT: 0 none, 1 colsum (atomicAdd emit_buf[i] += sum_s C[s,i]),
//         2 stats  (atomicAdd emit_buf[2r] += row-sum, [2r+1] += row-sumsq)
// Block: 256 thr, 16 rows x 64 cols. Grid: 768 = 3 colgroups x 256 rowgroups.
// =======================================================================
template <int EMIT, int LNL>
__global__ __launch_bounds__(256) void stage2_k(
    const float* __restrict__ A, const float* __restrict__ W,
    const float* __restrict__ bias,
    const float* __restrict__ stats_in, const float* __restrict__ lng,
    const float* __restrict__ lnb,
    float* __restrict__ out, float* __restrict__ emit_buf) {
    __shared__ float WT[DD * 64];   // swizzled: word j*64 + ((i' + 2*(j&31)) & 63)
    __shared__ float At[DD * 18];   // At[j*18 + r], r<16
    __shared__ float ms[16], rs[16];
    __shared__ float csum[4 * 64];

    const int t = threadIdx.x;
    const int tr = t >> 5, tc = t & 31;
    const int b = blockIdx.x;
    const int c0 = (b % 3) * 64;
    const int r0 = (b / 3) * 16;

    if (LNL > 0) {
        if (t < 16) {
            float s = stats_in[2 * (r0 + t)];
            float q = stats_in[2 * (r0 + t) + 1];
            float mean = s * (1.f / 192.f);
            float var = q * (1.f / 192.f) - mean * mean;
            ms[t] = mean;
            rs[t] = rsqrtf(var + 1e-5f);
        }
        __syncthreads();
    }

    // ---- stage A tile (16 x 192), applying LN on load if requested ----
    {
        const float4* A4 = (const float4*)(A + (size_t)r0 * DD);
#pragma unroll
        for (int q = 0; q < 3; q++) {
            int fidx = t + 256 * q;            // < 768
            int r = fidx / 48, jj = fidx - r * 48;
            float4 v = A4[fidx];
            if (LNL > 0) {
                float mean = ms[r], rstd = rs[r];
                float4 g4 = ((const float4*)lng)[jj];
                float4 b4 = ((const float4*)lnb)[jj];
                v.x = (v.x - mean) * rstd * g4.x + b4.x;
                v.y = (v.y - mean) * rstd * g4.y + b4.y;
                v.z = (v.z - mean) * rstd * g4.z + b4.z;
                v.w = (v.w - mean) * rstd * g4.w + b4.w;
                if (LNL == 2) {
                    v.x = fmaxf(v.x, 0.f); v.y = fmaxf(v.y, 0.f);
                    v.z = fmaxf(v.z, 0.f); v.w = fmaxf(v.w, 0.f);
                }
            }
            int j0 = 4 * jj;
            At[(j0 + 0) * 18 + r] = v.x;
            At[(j0 + 1) * 18 + r] = v.y;
            At[(j0 + 2) * 18 + r] = v.z;
            At[(j0 + 3) * 18 + r] = v.w;
        }
    }
    // ---- stage W slice (64 x 192) transposed+swizzled ----
    {
        const float4* W4 = (const float4*)(W + (size_t)c0 * DD);
#pragma unroll
        for (int q = 0; q < 12; q++) {
            int fidx = t + 256 * q;            // < 3072
            int ip = fidx / 48, jj = fidx - ip * 48;
            float4 v = W4[fidx];
            int j0 = 4 * jj;
            WT[(j0 + 0) * 64 + ((ip + 2 * ((j0 + 0) & 31)) & 63)] = v.x;
            WT[(j0 + 1) * 64 + ((ip + 2 * ((j0 + 1) & 31)) & 63)] = v.y;
            WT[(j0 + 2) * 64 + ((ip + 2 * ((j0 + 2) & 31)) & 63)] = v.z;
            WT[(j0 + 3) * 64 + ((ip + 2 * ((j0 + 3) & 31)) & 63)] = v.w;
        }
    }

    const int i0 = c0 + 2 * tc;
    float b0v = bias[i0], b1v = bias[i0 + 1];
    float acc00 = b0v, acc01 = b1v, acc10 = b0v, acc11 = b1v;
    __syncthreads();

#pragma unroll 4
    for (int j = 0; j < DD; j++) {
        float2 a2 = *(const float2*)&At[j * 18 + 2 * tr];
        int cs = (2 * tc + 2 * (j & 31)) & 63;
        float2 w2 = *(const float2*)&WT[j * 64 + cs];
        acc00 = fmaf(a2.x, w2.x, acc00);
        acc01 = fmaf(a2.x, w2.y, acc01);
        acc10 = fmaf(a2.y, w2.x, acc10);
        acc11 = fmaf(a2.y, w2.y, acc11);
    }

    const int ra = r0 + 2 * tr, rb = ra + 1;
    *(float2*)&out[(size_t)ra * DD + i0] = make_float2(acc00, acc01);
    *(float2*)&out[(size_t)rb * DD + i0] = make_float2(acc10, acc11);

    if (EMIT == 2) {
        float s0 = acc00 + acc01, q0 = acc00 * acc00 + acc01 * acc01;
        float s1 = acc10 + acc11, q1 = acc10 * acc10 + acc11 * acc11;
#pragma unroll
        for (int m = 16; m >= 1; m >>= 1) {
            s0 += __shfl_xor(s0, m); q0 += __shfl_xor(q0, m);
            s1 += __shfl_xor(s1, m); q1 += __shfl_xor(q1, m);
        }
        if (tc == 0) {
            atomicAdd(&emit_buf[2 * ra], s0);
            atomicAdd(&emit_buf[2 * ra + 1], q0);
            atomicAdd(&emit_buf[2 * rb], s1);
            atomicAdd(&emit_buf[2 * rb + 1], q1);
        }
    } else if (EMIT == 1) {
        float cs0 = acc00 + acc10;   // col i0, this thread's 2 rows
        float cs1 = acc01 + acc11;   // col i0+1
        cs0 += __shfl_xor(cs0, 32);  // fold the other tr in this wave
        cs1 += __shfl_xor(cs1, 32);
        int w = t >> 6;
        if ((t & 63) < 32) {
            csum[w * 64 + 2 * tc] = cs0;
            csum[w * 64 + 2 * tc + 1] = cs1;
        }
        __syncthreads();
        if (t < 64) {
            float s = csum[t] + csum[64 + t] + csum[128 + t] + csum[192 + t];
            atomicAdd(&emit_buf[c0 + t], s);
        }
    }
}

// =======================================================================
// hyper_k: combined hypernet weights, 32 AW-rows per block, coalesced.
//   b < 1152          : Wt[k]  = tm_W[k] + tm_AW[k,:]@a0 + tm_Ab[k]
//   b < 2304          : Wc[k]  = cm_W[k] + ...
//   else (e = expert) : Wmoe[k] += gate[e]*(ex_W[e,k] + ex_AW[e,k,:]@a0 + ex_Ab[e,k])
// =======================================================================
__global__ __launch_bounds__(256) void hyper_k(
    const float* __restrict__ tm_W, const float* __restrict__ tm_AW,
    const float* __restrict__ tm_Ab, const float* __restrict__ cm_W,
    const float* __restrict__ cm_AW, const float* __restrict__ cm_Ab,
    const float* __restrict__ ex_W, const float* __restrict__ ex_AW,
    const float* __restrict__ ex_Ab, const float* __restrict__ a0g,
    const float* __restrict__ gateg, float* __restrict__ Wt,
    float* __restrict__ Wc, float* __restrict__ Wmoe) {
    __shared__ float a0s[DD];
    __shared__ float rows[32 * 204];
    __shared__ float wb[32], ab[32], vals[32];
    const int t = threadIdx.x;
    const int b = blockIdx.x;
    const float* AW; const float* WB; const float* AB;
    int k0, mode, e = 0;
    if (b < 1152)      { mode = 0; AW = tm_AW; WB = tm_W; AB = tm_Ab; k0 = b * 32; }
    else if (b < 2304) { mode = 1; AW = cm_AW; WB = cm_W; AB = cm_Ab; k0 = (b - 1152) * 32; }
    else {
        mode = 2; int bb = b - 2304; e = bb / 1152; k0 = (bb - e * 1152) * 32;
        AW = ex_AW + (size_t)e * 36864 * DD;
        WB = ex_W + (size_t)e * 36864;
        AB = ex_Ab + (size_t)e * 36864;
    }
    if (t < DD) a0s[t] = a0g[t];
    if (t < 32) { wb[t] = WB[k0 + t]; ab[t] = AB[k0 + t]; }
    const float4* src4 = (const float4*)(AW + (size_t)k0 * DD);
#pragma unroll
    for (int q = 0; q < 6; q++) {
        int fidx = t + 256 * q;            // < 1536
        int r = fidx / 48, jj = fidx - r * 48;
        float4 v = src4[fidx];
        *(float4*)&rows[r * 204 + 4 * jj] = v;
    }
    __syncthreads();
    const int r = t >> 3, p = t & 7;
    float acc = 0.f;
#pragma unroll
    for (int q = 0; q < 6; q++) {
        int jo = p * 24 + 4 * q;
        float4 w = *(const float4*)&rows[r * 204 + jo];
        float4 aa = *(const float4*)&a0s[jo];
        acc = fmaf(w.x, aa.x, acc); acc = fmaf(w.y, aa.y, acc);
        acc = fmaf(w.z, aa.z, acc); acc = fmaf(w.w, aa.w, acc);
    }
    acc += __shfl_xor(acc, 1);
    acc += __shfl_xor(acc, 2);
    acc += __shfl_xor(acc, 4);
    if (p == 0) vals[r] = acc + wb[r] + ab[r];
    __syncthreads();
    if (t < 32) {
        if (mode == 0) Wt[k0 + t] = vals[t];
        else if (mode == 1) Wc[k0 + t] = vals[t];
        else atomicAdd(&Wmoe[k0 + t], gateg[e] * vals[t]);
    }
}

// =======================================================================
// feat2_k: a_pre[i] += sum_{j in chunk} xm[j]*(feat_W[k]+feat_AW[k,:]@xm+feat_Ab[k])
//   (feat_b added later in vec_k). 1152 blocks x 32 rows.
// =======================================================================
__global__ __launch_bounds__(256) void feat2_k(
    const float* __restrict__ feat_W, const float* __restrict__ feat_AW,
    const float* __restrict__ feat_Ab, const float* __restrict__ xm_sum,
    float* __restrict__ a_pre) {
    __shared__ float xms[DD];
    __shared__ float rows[32 * 204];
    __shared__ float wb[32], ab[32], vals[32];
    const int t = threadIdx.x;
    const int k0 = blockIdx.x * 32;
    if (t < DD) xms[t] = xm_sum[t] * (1.f / 4096.f);
    if (t < 32) { wb[t] = feat_W[k0 + t]; ab[t] = feat_Ab[k0 + t]; }
    const float4* src4 = (const float4*)(feat_AW + (size_t)k0 * DD);
#pragma unroll
    for (int q = 0; q < 6; q++) {
        int fidx = t + 256 * q;
        int r = fidx / 48, jj = fidx - r * 48;
        float4 v = src4[fidx];
        *(float4*)&rows[r * 204 + 4 * jj] = v;
    }
    __syncthreads();
    const int r = t >> 3, p = t & 7;
    float acc = 0.f;
#pragma unroll
    for (int q = 0; q < 6; q++) {
        int jo = p * 24 + 4 * q;
        float4 w = *(const float4*)&rows[r * 204 + jo];
        float4 aa = *(const float4*)&xms[jo];
        acc = fmaf(w.x, aa.x, acc); acc = fmaf(w.y, aa.y, acc);
        acc = fmaf(w.z, aa.z, acc); acc = fmaf(w.w, aa.w, acc);
    }
    acc += __shfl_xor(acc, 1);
    acc += __shfl_xor(acc, 2);
    acc += __shfl_xor(acc, 4);
    if (p == 0) vals[r] = acc + wb[r] + ab[r];
    __syncthreads();
    const int j0 = k0 % DD;   // chunk of 32 stays within one output i
    if (t < 32) {
        float c = vals[t] * xms[j0 + t];
#pragma unroll
        for (int m = 16; m >= 1; m >>= 1) c += __shfl_xor(c, m);
        if (t == 0) atomicAdd(&a_pre[k0 / DD], c);
    }
}

// =======================================================================
// vec_k: a0 = LN(a_pre + feat_b); gate = softmax(a0@gate_W^T + gate_b);
//        b_moe = sum_e gate[e]*ex_b[e,:]
// =======================================================================
__global__ __launch_bounds__(192) void vec_k(
    const float* __restrict__ a_pre, const float* __restrict__ feat_b,
    const float* __restrict__ an_g, const float* __restrict__ an_b,
    const float* __restrict__ gate_W, const float* __restrict__ gate_b,
    const float* __restrict__ ex_b, float* __restrict__ a0g,
    float* __restrict__ gateg, float* __restrict__ b_moe) {
    __shared__ float lgs[8];
    __shared__ float red[6];
    const int t = threadIdx.x;
    float v = a_pre[t] + feat_b[t];
    float s = v, q = v * v;
#pragma unroll
    for (int m = 32; m >= 1; m >>= 1) {
        s += __shfl_xor(s, m);
        q += __shfl_xor(q, m);
    }
    if ((t & 63) == 0) { red[t >> 6] = s; red[3 + (t >> 6)] = q; }
    if (t < 8) lgs[t] = gate_b[t];
    __syncthreads();
    float S = red[0] + red[1] + red[2];
    float Q = red[3] + red[4] + red[5];
    float mean = S * (1.f / 192.f);
    float var = Q * (1.f / 192.f) - mean * mean;
    float rstd = rsqrtf(var + 1e-5f);
    float a0v = (v - mean) * rstd * an_g[t] + an_b[t];
    a0g[t] = a0v;
#pragma unroll
    for (int e = 0; e < 8; e++) atomicAdd(&lgs[e], a0v * gate_W[e * DD + t]);
    __syncthreads();
    if (t == 0) {
        float mx = lgs[0];
        for (int e = 1; e < 8; e++) mx = fmaxf(mx, lgs[e]);
        float sum = 0.f, ex[8];
        for (int e = 0; e < 8; e++) { ex[e] = expf(lgs[e] - mx); sum += ex[e]; }
        for (int e = 0; e < 8; e++) lgs[e] = ex[e] / sum;
    }
    __syncthreads();
    if (t < 8) gateg[t] = lgs[t];
    float bm = 0.f;
#pragma unroll
    for (int e = 0; e < 8; e++) bm = fmaf(lgs[e], ex_b[e * DD + t], bm);
    b_moe[t] = bm;
}

// =======================================================================
extern "C" void kernel_launch(void* const* d_in, const int* in_sizes, int n_in,
                              void* d_out, int out_size, void* d_ws, size_t ws_size,
                              hipStream_t stream) {
    (void)in_sizes; (void)n_in; (void)out_size; (void)ws_size;
    const float* x       = (const float*)d_in[0];
    const float* W_in    = (const float*)d_in[1];
    const float* b_in    = (const float*)d_in[2];
    const float* feat_W  = (const float*)d_in[3];
    const float* feat_b  = (const float*)d_in[4];
    const float* feat_AW = (const float*)d_in[5];
    const float* feat_Ab = (const float*)d_in[6];
    const float* an_g    = (const float*)d_in[7];
    const float* an_b    = (const float*)d_in[8];
    const float* tm_W    = (const float*)d_in[9];
    const float* tm_b    = (const float*)d_in[10];
    const float* tm_AW   = (const float*)d_in[11];
    const float* tm_Ab   = (const float*)d_in[12];
    const float* tn_g    = (const float*)d_in[13];
    const float* tn_b    = (const float*)d_in[14];
    const float* cm_W    = (const float*)d_in[15];
    const float* cm_b    = (const float*)d_in[16];
    const float* cm_AW   = (const float*)d_in[17];
    const float* cm_Ab   = (const float*)d_in[18];
    const float* cn_g    = (const float*)d_in[19];
    const float* cn_b    = (const float*)d_in[20];
    const float* pm_W    = (const float*)d_in[21];
    const float* pm_b    = (const float*)d_in[22];
    const float* gate_W  = (const float*)d_in[23];
    const float* gate_b  = (const float*)d_in[24];
    const float* ex_W    = (const float*)d_in[25];
    const float* ex_b    = (const float*)d_in[26];
    const float* ex_AW   = (const float*)d_in[27];
    const float* ex_Ab   = (const float*)d_in[28];
    const float* mn_g    = (const float*)d_in[29];
    const float* mn_b    = (const float*)d_in[30];
    const float* out_W   = (const float*)d_in[31];
    const float* out_b   = (const float*)d_in[32];

    float* ws = (float*)d_ws;
    float* B0     = ws;                 // 786432
    float* B1     = ws + 786432;        // 786432
    float* xm_sum = ws + 1572864;       // 192    [zeroed]
    float* a_pre  = ws + 1573056;       // 192    [zeroed]
    float* st1    = ws + 1573248;       // 8192   [zeroed]
    float* st2    = ws + 1581440;       // 8192   [zeroed]
    float* st3    = ws + 1589632;       // 8192   [zeroed]
    float* Wmoe   = ws + 1597824;       // 36864  [zeroed]
    float* Wt     = ws + 1634688;       // 36864
    float* Wc     = ws + 1671552;       // 36864
    float* a0     = ws + 1708416;       // 192
    float* gate   = ws + 1708608;       // 8
    float* b_moe  = ws + 1708616;       // 192

    // zero the accumulated region (xm_sum .. Wmoe) in one shot
    hipMemsetAsync(xm_sum, 0, (size_t)61824 * sizeof(float), stream);

    // S1: h = x @ W_in^T + b_in ; colsum -> xm_sum        (x -> B0)
    stage2_k<1, 0><<<768, 256, 0, stream>>>(x, W_in, b_in, nullptr, nullptr, nullptr,
                                            B0, xm_sum);
    feat2_k<<<1152, 256, 0, stream>>>(feat_W, feat_AW, feat_Ab, xm_sum, a_pre);
    vec_k<<<1, 192, 0, stream>>>(a_pre, feat_b, an_g, an_b, gate_W, gate_b, ex_b,
                                 a0, gate, b_moe);
    hyper_k<<<11520, 256, 0, stream>>>(tm_W, tm_AW, tm_Ab, cm_W, cm_AW, cm_Ab,
                                       ex_W, ex_AW, ex_Ab, a0, gate, Wt, Wc, Wmoe);
    // S2: tpre = h @ Wt^T + tm_b ; stats -> st1           (B0 -> B1)
    stage2_k<2, 0><<<768, 256, 0, stream>>>(B0, Wt, tm_b, nullptr, nullptr, nullptr,
                                            B1, st1);
    // S3: cpre = LN_tn(tpre) @ Wc^T + cm_b ; stats -> st2 (B1 -> B0)
    stage2_k<2, 1><<<768, 256, 0, stream>>>(B1, Wc, cm_b, st1, tn_g, tn_b, B0, st2);
    // S4: m = LN_cn(cpre) @ pm_W^T + pm_b                 (B0 -> B1)
    stage2_k<0, 1><<<768, 256, 0, stream>>>(B0, pm_W, pm_b, st2, cn_g, cn_b, B1, nullptr);
    // S5: eopre = m @ Wmoe^T + b_moe ; stats -> st3       (B1 -> B0)
    stage2_k<2, 0><<<768, 256, 0, stream>>>(B1, Wmoe, b_moe, nullptr, nullptr, nullptr,
                                            B0, st3);
    // S6: out = relu(LN_mn(eopre)) @ out_W^T + out_b      (B0 -> d_out)
    stage2_k<0, 2><<<768, 256, 0, stream>>>(B0, out_W, out_b, st3, mn_g, mn_b,
                                            (float*)d_out, nullptr);
}

// Round 4
// 537.105 us; speedup vs baseline: 1.1048x; 1.0555x over previous
//
#include <hip/hip_runtime.h>

#define DD 192

// =======================================================================
// stage3_k: C[s,i] = sum_j A'[s,j] * W[i,j] + bias[i]
//   A' = A (LNL=0), LN(A) (LNL=1), relu(LN(A)) (LNL=2)
//   LN stats come from stats_in[3][8192] (3 colgroup banks, summed here).
//   EMIT: 0 none, 1 colsum (atomicAdd emit_buf[i] += sum_s C[s,i]),
//         2 stats  (emit_buf[cg*8192 + 2r] = row-sum, +1 = row-sumsq; non-atomic)
// Block: 256 thr = 8 tr x 32 tc; tile 32 rows x 64 cols; thread = 4r x 2c.
// Grid: 384 = 3 colgroups x 128 rowgroups.
// =======================================================================
template <int EMIT, int LNL>
__global__ __launch_bounds__(256) void stage3_k(
    const float* __restrict__ A, const float* __restrict__ W,
    const float* __restrict__ bias,
    const float* __restrict__ stats_in, const float* __restrict__ lng,
    const float* __restrict__ lnb,
    float* __restrict__ out, float* __restrict__ emit_buf) {
    __shared__ float At[32 * 200];   // row-major, stride 200 (bank-stride 8)
    __shared__ float WT[DD * 64];    // swizzled: word j*64 + ((ip + 2*(j&31)) & 63)
    __shared__ float ms[32], rs[32];
    __shared__ float csum[4 * 64];

    const int t = threadIdx.x;
    const int tr = t >> 5, tc = t & 31;
    const int b = blockIdx.x;
    const int cg = b % 3;
    const int c0 = cg * 64;
    const int r0 = (b / 3) * 32;

    if (LNL > 0) {
        if (t < 32) {
            int r = r0 + t;
            float s = stats_in[2 * r] + stats_in[8192 + 2 * r] + stats_in[16384 + 2 * r];
            float q = stats_in[2 * r + 1] + stats_in[8192 + 2 * r + 1]
                    + stats_in[16384 + 2 * r + 1];
            float mean = s * (1.f / 192.f);
            float var = q * (1.f / 192.f) - mean * mean;
            ms[t] = mean;
            rs[t] = rsqrtf(var + 1e-5f);
        }
        __syncthreads();
    }

    // ---- stage A tile (32 x 192), applying LN(+ReLU) on load ----
    {
        const float4* A4 = (const float4*)(A + (size_t)r0 * DD);
#pragma unroll
        for (int q = 0; q < 6; q++) {
            int f = t + 256 * q;               // < 1536
            int r = f / 48, jj = f - r * 48;
            float4 v = A4[f];
            if (LNL > 0) {
                float mean = ms[r], rstd = rs[r];
                float4 g4 = ((const float4*)lng)[jj];
                float4 b4 = ((const float4*)lnb)[jj];
                v.x = (v.x - mean) * rstd * g4.x + b4.x;
                v.y = (v.y - mean) * rstd * g4.y + b4.y;
                v.z = (v.z - mean) * rstd * g4.z + b4.z;
                v.w = (v.w - mean) * rstd * g4.w + b4.w;
                if (LNL == 2) {
                    v.x = fmaxf(v.x, 0.f); v.y = fmaxf(v.y, 0.f);
                    v.z = fmaxf(v.z, 0.f); v.w = fmaxf(v.w, 0.f);
                }
            }
            *(float4*)&At[r * 200 + 4 * jj] = v;
        }
    }
    // ---- stage W slice (64 x 192) transposed+swizzled ----
    {
        const float4* W4 = (const float4*)(W + (size_t)c0 * DD);
#pragma unroll
        for (int q = 0; q < 12; q++) {
            int f = t + 256 * q;               // < 3072
            int ip = f / 48, jj = f - ip * 48;
            float4 v = W4[f];
            int j0 = 4 * jj;
            WT[(j0 + 0) * 64 + ((ip + 2 * ((j0 + 0) & 31)) & 63)] = v.x;
            WT[(j0 + 1) * 64 + ((ip + 2 * ((j0 + 1) & 31)) & 63)] = v.y;
            WT[(j0 + 2) * 64 + ((ip + 2 * ((j0 + 2) & 31)) & 63)] = v.z;
            WT[(j0 + 3) * 64 + ((ip + 2 * ((j0 + 3) & 31)) & 63)] = v.w;
        }
    }

    const int i0 = c0 + 2 * tc;
    float bv0 = bias[i0], bv1 = bias[i0 + 1];
    float acc[4][2];
#pragma unroll
    for (int i = 0; i < 4; i++) { acc[i][0] = bv0; acc[i][1] = bv1; }
    __syncthreads();

    const int rbase = 4 * tr;
#pragma unroll 4
    for (int j = 0; j < DD; j++) {
        int cs = (2 * tc + 2 * (j & 31)) & 63;
        float2 w2 = *(const float2*)&WT[j * 64 + cs];
        float a0 = At[(rbase + 0) * 200 + j];
        float a1 = At[(rbase + 1) * 200 + j];
        float a2 = At[(rbase + 2) * 200 + j];
        float a3 = At[(rbase + 3) * 200 + j];
        acc[0][0] = fmaf(a0, w2.x, acc[0][0]); acc[0][1] = fmaf(a0, w2.y, acc[0][1]);
        acc[1][0] = fmaf(a1, w2.x, acc[1][0]); acc[1][1] = fmaf(a1, w2.y, acc[1][1]);
        acc[2][0] = fmaf(a2, w2.x, acc[2][0]); acc[2][1] = fmaf(a2, w2.y, acc[2][1]);
        acc[3][0] = fmaf(a3, w2.x, acc[3][0]); acc[3][1] = fmaf(a3, w2.y, acc[3][1]);
    }

#pragma unroll
    for (int i = 0; i < 4; i++) {
        int row = r0 + rbase + i;
        *(float2*)&out[(size_t)row * DD + i0] = make_float2(acc[i][0], acc[i][1]);
    }

    if (EMIT == 2) {
#pragma unroll
        for (int i = 0; i < 4; i++) {
            float s = acc[i][0] + acc[i][1];
            float q = acc[i][0] * acc[i][0] + acc[i][1] * acc[i][1];
#pragma unroll
            for (int m = 16; m >= 1; m >>= 1) {
                s += __shfl_xor(s, m);
                q += __shfl_xor(q, m);
            }
            if (tc == 0) {
                int r = r0 + rbase + i;
                emit_buf[cg * 8192 + 2 * r] = s;
                emit_buf[cg * 8192 + 2 * r + 1] = q;
            }
        }
    } else if (EMIT == 1) {
        float cs0 = acc[0][0] + acc[1][0] + acc[2][0] + acc[3][0];
        float cs1 = acc[0][1] + acc[1][1] + acc[2][1] + acc[3][1];
        cs0 += __shfl_xor(cs0, 32);   // fold tr-pair within wave
        cs1 += __shfl_xor(cs1, 32);
        int w = t >> 6;
        if ((t & 63) < 32) {
            csum[w * 64 + 2 * tc] = cs0;
            csum[w * 64 + 2 * tc + 1] = cs1;
        }
        __syncthreads();
        if (t < 64) {
            float s = csum[t] + csum[64 + t] + csum[128 + t] + csum[192 + t];
            atomicAdd(&emit_buf[c0 + t], s);
        }
    }
}

// =======================================================================
// hyper_k: combined hypernet weights, 32 AW-rows per block, coalesced.
// =======================================================================
__global__ __launch_bounds__(256) void hyper_k(
    const float* __restrict__ tm_W, const float* __restrict__ tm_AW,
    const float* __restrict__ tm_Ab, const float* __restrict__ cm_W,
    const float* __restrict__ cm_AW, const float* __restrict__ cm_Ab,
    const float* __restrict__ ex_W, const float* __restrict__ ex_AW,
    const float* __restrict__ ex_Ab, const float* __restrict__ a0g,
    const float* __restrict__ gateg, float* __restrict__ Wt,
    float* __restrict__ Wc, float* __restrict__ Wmoe) {
    __shared__ float a0s[DD];
    __shared__ float rows[32 * 204];
    __shared__ float wb[32], ab[32], vals[32];
    const int t = threadIdx.x;
    const int b = blockIdx.x;
    const float* AW; const float* WB; const float* AB;
    int k0, mode, e = 0;
    if (b < 1152)      { mode = 0; AW = tm_AW; WB = tm_W; AB = tm_Ab; k0 = b * 32; }
    else if (b < 2304) { mode = 1; AW = cm_AW; WB = cm_W; AB = cm_Ab; k0 = (b - 1152) * 32; }
    else {
        mode = 2; int bb = b - 2304; e = bb / 1152; k0 = (bb - e * 1152) * 32;
        AW = ex_AW + (size_t)e * 36864 * DD;
        WB = ex_W + (size_t)e * 36864;
        AB = ex_Ab + (size_t)e * 36864;
    }
    if (t < DD) a0s[t] = a0g[t];
    if (t < 32) { wb[t] = WB[k0 + t]; ab[t] = AB[k0 + t]; }
    const float4* src4 = (const float4*)(AW + (size_t)k0 * DD);
#pragma unroll
    for (int q = 0; q < 6; q++) {
        int fidx = t + 256 * q;            // < 1536
        int r = fidx / 48, jj = fidx - r * 48;
        float4 v = src4[fidx];
        *(float4*)&rows[r * 204 + 4 * jj] = v;
    }
    __syncthreads();
    const int r = t >> 3, p = t & 7;
    float acc = 0.f;
#pragma unroll
    for (int q = 0; q < 6; q++) {
        int jo = p * 24 + 4 * q;
        float4 w = *(const float4*)&rows[r * 204 + jo];
        float4 aa = *(const float4*)&a0s[jo];
        acc = fmaf(w.x, aa.x, acc); acc = fmaf(w.y, aa.y, acc);
        acc = fmaf(w.z, aa.z, acc); acc = fmaf(w.w, aa.w, acc);
    }
    acc += __shfl_xor(acc, 1);
    acc += __shfl_xor(acc, 2);
    acc += __shfl_xor(acc, 4);
    if (p == 0) vals[r] = acc + wb[r] + ab[r];
    __syncthreads();
    if (t < 32) {
        if (mode == 0) Wt[k0 + t] = vals[t];
        else if (mode == 1) Wc[k0 + t] = vals[t];
        else atomicAdd(&Wmoe[k0 + t], gateg[e] * vals[t]);
    }
}

// =======================================================================
// feat2_k: a_pre[i] += sum_{j in chunk} xm[j]*(feat_W[k]+feat_AW[k,:]@xm+feat_Ab[k])
// =======================================================================
__global__ __launch_bounds__(256) void feat2_k(
    const float* __restrict__ feat_W, const float* __restrict__ feat_AW,
    const float* __restrict__ feat_Ab, const float* __restrict__ xm_sum,
    float* __restrict__ a_pre) {
    __shared__ float xms[DD];
    __shared__ float rows[32 * 204];
    __shared__ float wb[32], ab[32], vals[32];
    const int t = threadIdx.x;
    const int k0 = blockIdx.x * 32;
    if (t < DD) xms[t] = xm_sum[t] * (1.f / 4096.f);
    if (t < 32) { wb[t] = feat_W[k0 + t]; ab[t] = feat_Ab[k0 + t]; }
    const float4* src4 = (const float4*)(feat_AW + (size_t)k0 * DD);
#pragma unroll
    for (int q = 0; q < 6; q++) {
        int fidx = t + 256 * q;
        int r = fidx / 48, jj = fidx - r * 48;
        float4 v = src4[fidx];
        *(float4*)&rows[r * 204 + 4 * jj] = v;
    }
    __syncthreads();
    const int r = t >> 3, p = t & 7;
    float acc = 0.f;
#pragma unroll
    for (int q = 0; q < 6; q++) {
        int jo = p * 24 + 4 * q;
        float4 w = *(const float4*)&rows[r * 204 + jo];
        float4 aa = *(const float4*)&xms[jo];
        acc = fmaf(w.x, aa.x, acc); acc = fmaf(w.y, aa.y, acc);
        acc = fmaf(w.z, aa.z, acc); acc = fmaf(w.w, aa.w, acc);
    }
    acc += __shfl_xor(acc, 1);
    acc += __shfl_xor(acc, 2);
    acc += __shfl_xor(acc, 4);
    if (p == 0) vals[r] = acc + wb[r] + ab[r];
    __syncthreads();
    const int j0 = k0 % DD;   // chunk of 32 stays within one output i
    if (t < 32) {
        float c = vals[t] * xms[j0 + t];
#pragma unroll
        for (int m = 16; m >= 1; m >>= 1) c += __shfl_xor(c, m);
        if (t == 0) atomicAdd(&a_pre[k0 / DD], c);
    }
}

// =======================================================================
// vec_k: a0 = LN(a_pre + feat_b); gate = softmax(a0@gate_W^T + gate_b);
//        b_moe = sum_e gate[e]*ex_b[e,:]
// =======================================================================
__global__ __launch_bounds__(192) void vec_k(
    const float* __restrict__ a_pre, const float* __restrict__ feat_b,
    const float* __restrict__ an_g, const float* __restrict__ an_b,
    const float* __restrict__ gate_W, const float* __restrict__ gate_b,
    const float* __restrict__ ex_b, float* __restrict__ a0g,
    float* __restrict__ gateg, float* __restrict__ b_moe) {
    __shared__ float lgs[8];
    __shared__ float red[6];
    const int t = threadIdx.x;
    float v = a_pre[t] + feat_b[t];
    float s = v, q = v * v;
#pragma unroll
    for (int m = 32; m >= 1; m >>= 1) {
        s += __shfl_xor(s, m);
        q += __shfl_xor(q, m);
    }
    if ((t & 63) == 0) { red[t >> 6] = s; red[3 + (t >> 6)] = q; }
    if (t < 8) lgs[t] = gate_b[t];
    __syncthreads();
    float S = red[0] + red[1] + red[2];
    float Q = red[3] + red[4] + red[5];
    float mean = S * (1.f / 192.f);
    float var = Q * (1.f / 192.f) - mean * mean;
    float rstd = rsqrtf(var + 1e-5f);
    float a0v = (v - mean) * rstd * an_g[t] + an_b[t];
    a0g[t] = a0v;
#pragma unroll
    for (int e = 0; e < 8; e++) atomicAdd(&lgs[e], a0v * gate_W[e * DD + t]);
    __syncthreads();
    if (t == 0) {
        float mx = lgs[0];
        for (int e = 1; e < 8; e++) mx = fmaxf(mx, lgs[e]);
        float sum = 0.f, ex[8];
        for (int e = 0; e < 8; e++) { ex[e] = expf(lgs[e] - mx); sum += ex[e]; }
        for (int e = 0; e < 8; e++) lgs[e] = ex[e] / sum;
    }
    __syncthreads();
    if (t < 8) gateg[t] = lgs[t];
    float bm = 0.f;
#pragma unroll
    for (int e = 0; e < 8; e++) bm = fmaf(lgs[e], ex_b[e * DD + t], bm);
    b_moe[t] = bm;
}

// =======================================================================
extern "C" void kernel_launch(void* const* d_in, const int* in_sizes, int n_in,
                              void* d_out, int out_size, void* d_ws, size_t ws_size,
                              hipStream_t stream) {
    (void)in_sizes; (void)n_in; (void)out_size; (void)ws_size;
    const float* x       = (const float*)d_in[0];
    const float* W_in    = (const float*)d_in[1];
    const float* b_in    = (const float*)d_in[2];
    const float* feat_W  = (const float*)d_in[3];
    const float* feat_b  = (const float*)d_in[4];
    const float* feat_AW = (const float*)d_in[5];
    const float* feat_Ab = (const float*)d_in[6];
    const float* an_g    = (const float*)d_in[7];
    const float* an_b    = (const float*)d_in[8];
    const float* tm_W    = (const float*)d_in[9];
    const float* tm_b    = (const float*)d_in[10];
    const float* tm_AW   = (const float*)d_in[11];
    const float* tm_Ab   = (const float*)d_in[12];
    const float* tn_g    = (const float*)d_in[13];
    const float* tn_b    = (const float*)d_in[14];
    const float* cm_W    = (const float*)d_in[15];
    const float* cm_b    = (const float*)d_in[16];
    const float* cm_AW   = (const float*)d_in[17];
    const float* cm_Ab   = (const float*)d_in[18];
    const float* cn_g    = (const float*)d_in[19];
    const float* cn_b    = (const float*)d_in[20];
    const float* pm_W    = (const float*)d_in[21];
    const float* pm_b    = (const float*)d_in[22];
    const float* gate_W  = (const float*)d_in[23];
    const float* gate_b  = (const float*)d_in[24];
    const float* ex_W    = (const float*)d_in[25];
    const float* ex_b    = (const float*)d_in[26];
    const float* ex_AW   = (const float*)d_in[27];
    const float* ex_Ab   = (const float*)d_in[28];
    const float* mn_g    = (const float*)d_in[29];
    const float* mn_b    = (const float*)d_in[30];
    const float* out_W   = (const float*)d_in[31];
    const float* out_b   = (const float*)d_in[32];

    float* ws = (float*)d_ws;
    float* B0     = ws;                 // 786432
    float* B1     = ws + 786432;        // 786432
    float* xm_sum = ws + 1572864;       // 192    [zeroed]
    float* a_pre  = ws + 1573056;       // 192    [zeroed]
    float* Wmoe   = ws + 1573248;       // 36864  [zeroed]
    float* Wt     = ws + 1610112;       // 36864
    float* Wc     = ws + 1646976;       // 36864
    float* st1    = ws + 1683840;       // 3*8192 (not zeroed; fully written)
    float* st2    = ws + 1708416;       // 3*8192
    float* st3    = ws + 1732992;       // 3*8192
    float* a0     = ws + 1757568;       // 192
    float* gate   = ws + 1757760;       // 8
    float* b_moe  = ws + 1757768;       // 192

    // zero xm_sum + a_pre + Wmoe (contiguous)
    hipMemsetAsync(xm_sum, 0, (size_t)37248 * sizeof(float), stream);

    // S1: h = x @ W_in^T + b_in ; colsum -> xm_sum        (x -> B0)
    stage3_k<1, 0><<<384, 256, 0, stream>>>(x, W_in, b_in, nullptr, nullptr, nullptr,
                                            B0, xm_sum);
    feat2_k<<<1152, 256, 0, stream>>>(feat_W, feat_AW, feat_Ab, xm_sum, a_pre);
    vec_k<<<1, 192, 0, stream>>>(a_pre, feat_b, an_g, an_b, gate_W, gate_b, ex_b,
                                 a0, gate, b_moe);
    hyper_k<<<11520, 256, 0, stream>>>(tm_W, tm_AW, tm_Ab, cm_W, cm_AW, cm_Ab,
                                       ex_W, ex_AW, ex_Ab, a0, gate, Wt, Wc, Wmoe);
    // S2: tpre = h @ Wt^T + tm_b ; stats -> st1           (B0 -> B1)
    stage3_k<2, 0><<<384, 256, 0, stream>>>(B0, Wt, tm_b, nullptr, nullptr, nullptr,
                                            B1, st1);
    // S3: cpre = LN_tn(tpre) @ Wc^T + cm_b ; stats -> st2 (B1 -> B0)
    stage3_k<2, 1><<<384, 256, 0, stream>>>(B1, Wc, cm_b, st1, tn_g, tn_b, B0, st2);
    // S4: m = LN_cn(cpre) @ pm_W^T + pm_b                 (B0 -> B1)
    stage3_k<0, 1><<<384, 256, 0, stream>>>(B0, pm_W, pm_b, st2, cn_g, cn_b, B1, nullptr);
    // S5: eopre = m @ Wmoe^T + b_moe ; stats -> st3       (B1 -> B0)
    stage3_k<2, 0><<<384, 256, 0, stream>>>(B1, Wmoe, b_moe, nullptr, nullptr, nullptr,
                                            B0, st3);
    // S6: out = relu(LN_mn(eopre)) @ out_W^T + out_b      (B0 -> d_out)
    stage3_k<0, 2><<<384, 256, 0, stream>>>(B0, out_W, out_b, st3, mn_g, mn_b,
                                            (float*)d_out, nullptr);
}